// Round 1
// baseline (301.705 us; speedup 1.0000x reference)
//
#include <hip/hip_runtime.h>
#include <math.h>

typedef __attribute__((ext_vector_type(8))) short short8;
typedef __attribute__((ext_vector_type(4))) float floatx4;

#define T_SEQ 2048
#define NHEADS 16
#define HID 1024

__device__ __forceinline__ ushort f2b(float x){
  union { float f; unsigned u; } c; c.f = x;
  unsigned r = c.u + 0x7fffu + ((c.u >> 16) & 1u);
  return (ushort)(r >> 16);
}

__device__ __forceinline__ floatx4 fzero4(){
  floatx4 v; v[0]=0.f; v[1]=0.f; v[2]=0.f; v[3]=0.f; return v;
}

// ---------------- prep kernels ----------------

__global__ void cvt_f32_bf16(const float* __restrict__ in, ushort* __restrict__ out, int n4){
  int i = blockIdx.x * 256 + threadIdx.x;
  if (i < n4){
    float4 v = ((const float4*)in)[i];
    ushort4 o;
    o.x = f2b(v.x); o.y = f2b(v.y); o.z = f2b(v.z); o.w = f2b(v.w);
    ((ushort4*)out)[i] = o;
  }
}

// in: f32 [R][C]  ->  out: bf16 [C][R]
__global__ void transpose_cvt(const float* __restrict__ in, ushort* __restrict__ out, int R, int C){
  __shared__ float tile[32][33];
  int c0 = blockIdx.x * 32, r0 = blockIdx.y * 32;
  int tx = threadIdx.x & 31, ty = threadIdx.x >> 5;
  #pragma unroll
  for (int i = 0; i < 4; i++){
    int r = ty + i * 8;
    tile[r][tx] = in[(size_t)(r0 + r) * C + c0 + tx];
  }
  __syncthreads();
  #pragma unroll
  for (int i = 0; i < 4; i++){
    int r = ty + i * 8;
    out[(size_t)(c0 + r) * R + r0 + tx] = f2b(tile[tx][r]);
  }
}

__global__ void rope_tables(float* __restrict__ cosT, float* __restrict__ sinT){
  int idx = blockIdx.x * 256 + threadIdx.x;
  if (idx < T_SEQ * 32){
    int t = idx >> 5, i = idx & 31;
    float invf = powf(10000.0f, -(float)i / 32.0f);
    float a = (float)t * invf;
    cosT[idx] = cosf(a);
    sinT[idx] = sinf(a);
  }
}

// ---------------- GEMM1: qkv = hidden @ w_qkv + b, fused bias + RoPE + scatter ----------------
// A: [4096][1024] bf16, Bt: [3072][1024] bf16 (w_qkv transposed)
// outputs q,k,v: [B][NH][T][64] bf16

__global__ __launch_bounds__(256) void gemm_qkv(
    const ushort* __restrict__ A, const ushort* __restrict__ Bt,
    const float* __restrict__ bias,
    ushort* __restrict__ qO, ushort* __restrict__ kO, ushort* __restrict__ vO,
    const float* __restrict__ cosT, const float* __restrict__ sinT)
{
  __shared__ __align__(16) ushort As[128][40];
  __shared__ __align__(16) ushort Bs[128][40];
  int tid = threadIdx.x;
  int bm = blockIdx.x, bn = blockIdx.y;
  int wave = tid >> 6, lane = tid & 63;
  int wm = wave >> 1, wn = wave & 1;
  int quad = lane >> 4, l15 = lane & 15;

  floatx4 acc[4][4];
  for (int i = 0; i < 4; i++) for (int j = 0; j < 4; j++) acc[i][j] = fzero4();

  for (int kt = 0; kt < 32; ++kt){
    #pragma unroll
    for (int i = 0; i < 2; i++){
      int idx = tid + i * 256;
      int row = idx >> 2, c8 = (idx & 3) * 8;
      *(short8*)&As[row][c8] = *(const short8*)&A[(size_t)(bm * 128 + row) * 1024 + kt * 32 + c8];
      *(short8*)&Bs[row][c8] = *(const short8*)&Bt[(size_t)(bn * 128 + row) * 1024 + kt * 32 + c8];
    }
    __syncthreads();
    short8 af[4], bfr[4];
    #pragma unroll
    for (int i = 0; i < 4; i++) af[i]  = *(const short8*)&As[wm * 64 + i * 16 + l15][quad * 8];
    #pragma unroll
    for (int i = 0; i < 4; i++) bfr[i] = *(const short8*)&Bs[wn * 64 + i * 16 + l15][quad * 8];
    #pragma unroll
    for (int mt = 0; mt < 4; mt++)
      #pragma unroll
      for (int nt = 0; nt < 4; nt++)
        acc[mt][nt] = __builtin_amdgcn_mfma_f32_16x16x32_bf16(af[mt], bfr[nt], acc[mt][nt], 0, 0, 0);
    __syncthreads();
  }

  // epilogue: each wave's 64-wide n-range is exactly one component block (q/k/v of one head)
  int g = bn * 2 + wn;          // 64-block index in n space, = 3*h + comp
  int h = g / 3, comp = g - h * 3;

  if (comp == 2){
    #pragma unroll
    for (int nt = 0; nt < 4; nt++){
      int d = nt * 16 + l15;
      float bv = bias[g * 64 + d];
      #pragma unroll
      for (int mt = 0; mt < 4; mt++)
        #pragma unroll
        for (int r = 0; r < 4; r++){
          int row = bm * 128 + wm * 64 + mt * 16 + quad * 4 + r;
          int t = row & (T_SEQ - 1), b_ = row >> 11;
          vO[(size_t)((b_ * NHEADS + h) * T_SEQ + t) * 64 + d] = f2b(acc[mt][nt][r] + bv);
        }
    }
  } else {
    ushort* outP = (comp == 0) ? qO : kO;
    #pragma unroll
    for (int nt = 0; nt < 4; nt++){
      int d = nt * 16 + l15;
      float bv = bias[g * 64 + d];
      float bp = bias[g * 64 + (d ^ 32)];
      int fi = d & 31;
      float sgn = (d < 32) ? -1.0f : 1.0f;
      #pragma unroll
      for (int mt = 0; mt < 4; mt++)
        #pragma unroll
        for (int r = 0; r < 4; r++){
          int row = bm * 128 + wm * 64 + mt * 16 + quad * 4 + r;
          int t = row & (T_SEQ - 1), b_ = row >> 11;
          float cv = cosT[t * 32 + fi], sv = sinT[t * 32 + fi];
          float val = acc[mt][nt][r] + bv;
          float pv  = acc[mt][nt ^ 2][r] + bp;   // element at d^32, same lane/row
          outP[(size_t)((b_ * NHEADS + h) * T_SEQ + t) * 64 + d] = f2b(val * cv + sgn * pv * sv);
        }
    }
  }
}

// ---------------- flash attention ----------------
// q,k,v: [B][NH][T][64] bf16 ; out oB: [B][T][NH][64] bf16 (= [4096][1024] row-major)

__global__ __launch_bounds__(256) void attn(
    const ushort* __restrict__ qB, const ushort* __restrict__ kB,
    const ushort* __restrict__ vB, const int* __restrict__ amask,
    ushort* __restrict__ oB)
{
  __shared__ __align__(16) ushort Ks[64][72];
  __shared__ __align__(16) ushort Vt[64][72];     // transposed: [d][key]
  __shared__ __align__(16) ushort Ps[4][16][72];  // per-wave P round-trip
  int tid = threadIdx.x;
  int bh = blockIdx.x;       // b*16+h
  int qt = blockIdx.y;       // q tile (64 rows)
  int b = bh >> 4, h = bh & 15;
  int wave = tid >> 6, lane = tid & 63;
  int quad = lane >> 4, l15 = lane & 15;
  int q0 = qt * 64;

  const ushort* Qb = qB + (size_t)bh * T_SEQ * 64;
  const ushort* Kb = kB + (size_t)bh * T_SEQ * 64;
  const ushort* Vb = vB + (size_t)bh * T_SEQ * 64;

  // A-fragments of this wave's 16 q rows (held in regs for whole kernel)
  int qrow_frag = q0 + wave * 16 + l15;
  short8 qf0 = *(const short8*)&Qb[(size_t)qrow_frag * 64 + quad * 8];
  short8 qf1 = *(const short8*)&Qb[(size_t)qrow_frag * 64 + 32 + quad * 8];

  float m_i[4], l_i[4];
  floatx4 oacc[4];
  #pragma unroll
  for (int r = 0; r < 4; r++){ m_i[r] = -1e30f; l_i[r] = 0.f; }
  #pragma unroll
  for (int nt = 0; nt < 4; nt++) oacc[nt] = fzero4();

  int nkb = qt + 1;  // causal: key blocks 0..qt
  for (int kb = 0; kb < nkb; ++kb){
    int k0 = kb * 64;
    // stage K (direct) and V (transposed)
    #pragma unroll
    for (int i = 0; i < 2; i++){
      int idx = tid + i * 256;
      int row = idx >> 3, c8 = (idx & 7) * 8;
      *(short8*)&Ks[row][c8] = *(const short8*)&Kb[(size_t)(k0 + row) * 64 + c8];
      short8 vv = *(const short8*)&Vb[(size_t)(k0 + row) * 64 + c8];
      #pragma unroll
      for (int j = 0; j < 8; j++) Vt[c8 + j][row] = (ushort)vv[j];
    }
    __syncthreads();

    // S = Q K^T  (16 q rows x 64 keys per wave)
    floatx4 sacc[4];
    #pragma unroll
    for (int nt = 0; nt < 4; nt++) sacc[nt] = fzero4();
    #pragma unroll
    for (int nt = 0; nt < 4; nt++){
      short8 kf0 = *(const short8*)&Ks[nt * 16 + l15][quad * 8];
      short8 kf1 = *(const short8*)&Ks[nt * 16 + l15][32 + quad * 8];
      sacc[nt] = __builtin_amdgcn_mfma_f32_16x16x32_bf16(qf0, kf0, sacc[nt], 0, 0, 0);
      sacc[nt] = __builtin_amdgcn_mfma_f32_16x16x32_bf16(qf1, kf1, sacc[nt], 0, 0, 0);
    }

    // mask + scale ; C-layout: row=quad*4+r, col=l15 (per 16-col tile nt)
    float p[4][4];
    float rmax[4];
    #pragma unroll
    for (int r = 0; r < 4; r++) rmax[r] = -1e30f;
    int padv[4];
    #pragma unroll
    for (int nt = 0; nt < 4; nt++) padv[nt] = amask[b * T_SEQ + k0 + nt * 16 + l15];
    #pragma unroll
    for (int nt = 0; nt < 4; nt++){
      int key = k0 + nt * 16 + l15;
      #pragma unroll
      for (int r = 0; r < 4; r++){
        int qq = q0 + wave * 16 + quad * 4 + r;
        float s = (key <= qq && padv[nt] != 0) ? sacc[nt][r] * 0.125f : -1e30f;
        p[nt][r] = s;
        rmax[r] = fmaxf(rmax[r], s);
      }
    }
    // row max across the 16 lanes of the quad
    #pragma unroll
    for (int r = 0; r < 4; r++){
      float v = rmax[r];
      v = fmaxf(v, __shfl_xor(v, 1));
      v = fmaxf(v, __shfl_xor(v, 2));
      v = fmaxf(v, __shfl_xor(v, 4));
      v = fmaxf(v, __shfl_xor(v, 8));
      rmax[r] = v;
    }
    float alpha[4], rsum[4];
    #pragma unroll
    for (int r = 0; r < 4; r++){
      float mnew = fmaxf(m_i[r], rmax[r]);
      alpha[r] = __expf(m_i[r] - mnew);
      m_i[r] = mnew;
      rsum[r] = 0.f;
    }
    #pragma unroll
    for (int nt = 0; nt < 4; nt++)
      #pragma unroll
      for (int r = 0; r < 4; r++){
        float e = __expf(p[nt][r] - m_i[r]);
        p[nt][r] = e;
        rsum[r] += e;
      }
    #pragma unroll
    for (int r = 0; r < 4; r++){
      float v = rsum[r];
      v += __shfl_xor(v, 1); v += __shfl_xor(v, 2);
      v += __shfl_xor(v, 4); v += __shfl_xor(v, 8);
      l_i[r] = l_i[r] * alpha[r] + v;
    }
    #pragma unroll
    for (int nt = 0; nt < 4; nt++)
      #pragma unroll
      for (int r = 0; r < 4; r++)
        oacc[nt][r] *= alpha[r];

    // P: C-layout -> A-layout via per-wave LDS
    #pragma unroll
    for (int nt = 0; nt < 4; nt++)
      #pragma unroll
      for (int r = 0; r < 4; r++)
        Ps[wave][quad * 4 + r][nt * 16 + l15] = f2b(p[nt][r]);
    __syncthreads();  // also guarantees Ps visibility (uniform across waves)

    short8 pa0 = *(const short8*)&Ps[wave][l15][quad * 8];
    short8 pa1 = *(const short8*)&Ps[wave][l15][32 + quad * 8];
    #pragma unroll
    for (int nt = 0; nt < 4; nt++){
      short8 vf0 = *(const short8*)&Vt[nt * 16 + l15][quad * 8];
      short8 vf1 = *(const short8*)&Vt[nt * 16 + l15][32 + quad * 8];
      oacc[nt] = __builtin_amdgcn_mfma_f32_16x16x32_bf16(pa0, vf0, oacc[nt], 0, 0, 0);
      oacc[nt] = __builtin_amdgcn_mfma_f32_16x16x32_bf16(pa1, vf1, oacc[nt], 0, 0, 0);
    }
    __syncthreads();  // before next stage overwrites Ks/Vt
  }

  // write O: [b][t][h][d]
  #pragma unroll
  for (int nt = 0; nt < 4; nt++){
    int d = nt * 16 + l15;
    #pragma unroll
    for (int r = 0; r < 4; r++){
      int t = q0 + wave * 16 + quad * 4 + r;
      float o = oacc[nt][r] / l_i[r];
      oB[(size_t)((b * T_SEQ + t) * NHEADS + h) * 64 + d] = f2b(o);
    }
  }
}

// ---------------- GEMM3: out = O @ w_out (f32 out) ----------------

__global__ __launch_bounds__(256) void gemm_out_k(
    const ushort* __restrict__ A, const ushort* __restrict__ Bt,
    float* __restrict__ out)
{
  __shared__ __align__(16) ushort As[128][40];
  __shared__ __align__(16) ushort Bs[128][40];
  int tid = threadIdx.x;
  int bm = blockIdx.x, bn = blockIdx.y;
  int wave = tid >> 6, lane = tid & 63;
  int wm = wave >> 1, wn = wave & 1;
  int quad = lane >> 4, l15 = lane & 15;

  floatx4 acc[4][4];
  for (int i = 0; i < 4; i++) for (int j = 0; j < 4; j++) acc[i][j] = fzero4();

  for (int kt = 0; kt < 32; ++kt){
    #pragma unroll
    for (int i = 0; i < 2; i++){
      int idx = tid + i * 256;
      int row = idx >> 2, c8 = (idx & 3) * 8;
      *(short8*)&As[row][c8] = *(const short8*)&A[(size_t)(bm * 128 + row) * 1024 + kt * 32 + c8];
      *(short8*)&Bs[row][c8] = *(const short8*)&Bt[(size_t)(bn * 128 + row) * 1024 + kt * 32 + c8];
    }
    __syncthreads();
    short8 af[4], bfr[4];
    #pragma unroll
    for (int i = 0; i < 4; i++) af[i]  = *(const short8*)&As[wm * 64 + i * 16 + l15][quad * 8];
    #pragma unroll
    for (int i = 0; i < 4; i++) bfr[i] = *(const short8*)&Bs[wn * 64 + i * 16 + l15][quad * 8];
    #pragma unroll
    for (int mt = 0; mt < 4; mt++)
      #pragma unroll
      for (int nt = 0; nt < 4; nt++)
        acc[mt][nt] = __builtin_amdgcn_mfma_f32_16x16x32_bf16(af[mt], bfr[nt], acc[mt][nt], 0, 0, 0);
    __syncthreads();
  }

  #pragma unroll
  for (int nt = 0; nt < 4; nt++){
    int n = bn * 128 + wn * 64 + nt * 16 + l15;
    #pragma unroll
    for (int mt = 0; mt < 4; mt++)
      #pragma unroll
      for (int r = 0; r < 4; r++){
        int row = bm * 128 + wm * 64 + mt * 16 + quad * 4 + r;
        out[(size_t)row * 1024 + n] = acc[mt][nt][r];
      }
  }
}

// ---------------- launch ----------------

extern "C" void kernel_launch(void* const* d_in, const int* in_sizes, int n_in,
                              void* d_out, int out_size, void* d_ws, size_t ws_size,
                              hipStream_t stream)
{
  const float* hidden = (const float*)d_in[0];   // [2][2048][1024] f32
  const int*   amask  = (const int*)d_in[1];     // [2][2048] i32
  const float* w_qkv  = (const float*)d_in[2];   // [1024][3072] f32
  const float* b_qkv  = (const float*)d_in[3];   // [3072] f32
  const float* w_out  = (const float*)d_in[4];   // [1024][1024] f32
  float* out = (float*)d_out;

  char* ws = (char*)d_ws;
  ushort* hO    = (ushort*)(ws);                 // 8 MB: hidden bf16, later reused as attn output O
  ushort* wqkvT = (ushort*)(ws + 8388608);       // 6 MB
  ushort* woutT = (ushort*)(ws + 14680064);      // 2 MB
  ushort* qB    = (ushort*)(ws + 16777216);      // 8 MB
  ushort* kB    = (ushort*)(ws + 25165824);      // 8 MB
  ushort* vB    = (ushort*)(ws + 33554432);      // 8 MB
  float*  cosT  = (float*)(ws + 41943040);       // 256 KB
  float*  sinT  = (float*)(ws + 42205184);       // 256 KB

  cvt_f32_bf16<<<4096, 256, 0, stream>>>(hidden, hO, 1048576);
  transpose_cvt<<<dim3(96, 32), 256, 0, stream>>>(w_qkv, wqkvT, 1024, 3072);
  transpose_cvt<<<dim3(32, 32), 256, 0, stream>>>(w_out, woutT, 1024, 1024);
  rope_tables<<<256, 256, 0, stream>>>(cosT, sinT);
  gemm_qkv<<<dim3(32, 24), 256, 0, stream>>>(hO, wqkvT, b_qkv, qB, kB, vB, cosT, sinT);
  attn<<<dim3(32, 32), 256, 0, stream>>>(qB, kB, vB, amask, hO /* reused as O */);
  gemm_out_k<<<dim3(32, 8), 256, 0, stream>>>(hO, woutT, out);
}

// Round 2
// 249.894 us; speedup vs baseline: 1.2073x; 1.2073x over previous
//
#include <hip/hip_runtime.h>
#include <math.h>

typedef __attribute__((ext_vector_type(8))) short short8;
typedef __attribute__((ext_vector_type(4))) float floatx4;

#define T_SEQ 2048
#define NHEADS 16
#define HID 1024

__device__ __forceinline__ ushort f2b(float x){
  union { float f; unsigned u; } c; c.f = x;
  unsigned r = c.u + 0x7fffu + ((c.u >> 16) & 1u);
  return (ushort)(r >> 16);
}

__device__ __forceinline__ floatx4 fzero4(){
  floatx4 v; v[0]=0.f; v[1]=0.f; v[2]=0.f; v[3]=0.f; return v;
}

// async global->LDS, 16B per lane, LDS dest = uniform base + lane*16
__device__ __forceinline__ void gl_lds16(const ushort* g, ushort* l){
  __builtin_amdgcn_global_load_lds(
      (const __attribute__((address_space(1))) void*)g,
      (__attribute__((address_space(3))) void*)l, 16, 0, 0);
}

// ---------------- prep kernels ----------------

__global__ void cvt_f32_bf16(const float* __restrict__ in, ushort* __restrict__ out, int n4){
  int i = blockIdx.x * 256 + threadIdx.x;
  if (i < n4){
    float4 v = ((const float4*)in)[i];
    ushort4 o;
    o.x = f2b(v.x); o.y = f2b(v.y); o.z = f2b(v.z); o.w = f2b(v.w);
    ((ushort4*)out)[i] = o;
  }
}

// in: f32 [R][C]  ->  out: bf16 [C][R]
__global__ void transpose_cvt(const float* __restrict__ in, ushort* __restrict__ out, int R, int C){
  __shared__ float tile[32][33];
  int c0 = blockIdx.x * 32, r0 = blockIdx.y * 32;
  int tx = threadIdx.x & 31, ty = threadIdx.x >> 5;
  #pragma unroll
  for (int i = 0; i < 4; i++){
    int r = ty + i * 8;
    tile[r][tx] = in[(size_t)(r0 + r) * C + c0 + tx];
  }
  __syncthreads();
  #pragma unroll
  for (int i = 0; i < 4; i++){
    int r = ty + i * 8;
    out[(size_t)(c0 + r) * R + r0 + tx] = f2b(tile[tx][r]);
  }
}

__global__ void rope_tables(float* __restrict__ cosT, float* __restrict__ sinT){
  int idx = blockIdx.x * 256 + threadIdx.x;
  if (idx < T_SEQ * 32){
    int t = idx >> 5, i = idx & 31;
    float invf = powf(10000.0f, -(float)i / 32.0f);
    float a = (float)t * invf;
    cosT[idx] = cosf(a);
    sinT[idx] = sinf(a);
  }
}

// ---------------- GEMM1: qkv = hidden @ w_qkv + b, fused bias + RoPE + scatter ----------------
// A: [4096][1024] bf16, Bt: [3072][1024] bf16 (w_qkv transposed)
// q,k: [B][NH][T][64] bf16 ; V written TRANSPOSED: vT [B][NH][64(d)][T] bf16

__global__ __launch_bounds__(256) void gemm_qkv(
    const ushort* __restrict__ A, const ushort* __restrict__ Bt,
    const float* __restrict__ bias,
    ushort* __restrict__ qO, ushort* __restrict__ kO, ushort* __restrict__ vT,
    const float* __restrict__ cosT, const float* __restrict__ sinT)
{
  __shared__ __align__(16) ushort As[128 * 32];   // [row][k], unpadded for global_load_lds
  __shared__ __align__(16) ushort Bs[128 * 32];
  int tid = threadIdx.x;
  int bm = blockIdx.x, bn = blockIdx.y;
  int wave = tid >> 6, lane = tid & 63;
  int wm = wave >> 1, wn = wave & 1;
  int quad = lane >> 4, l15 = lane & 15;

  // staging geometry: wave w stages rows [w*32, w*32+32) via 2 insts of 1KB each
  int srow0 = wave * 32 + (lane >> 2);   // chunk j adds j*16
  int scol  = (lane & 3) * 8;            // ushort offset in k
  ushort* ldsA0 = &As[wave * 1024];
  ushort* ldsA1 = &As[wave * 1024 + 512];
  ushort* ldsB0 = &Bs[wave * 1024];
  ushort* ldsB1 = &Bs[wave * 1024 + 512];

  floatx4 acc[4][4];
  for (int i = 0; i < 4; i++) for (int j = 0; j < 4; j++) acc[i][j] = fzero4();

  for (int kt = 0; kt < 32; ++kt){
    const ushort* gA = &A[(size_t)(bm * 128 + srow0) * 1024 + kt * 32 + scol];
    const ushort* gB = &Bt[(size_t)(bn * 128 + srow0) * 1024 + kt * 32 + scol];
    gl_lds16(gA, ldsA0);
    gl_lds16(gA + 16 * 1024, ldsA1);
    gl_lds16(gB, ldsB0);
    gl_lds16(gB + 16 * 1024, ldsB1);
    __syncthreads();
    short8 af[4], bfr[4];
    #pragma unroll
    for (int i = 0; i < 4; i++) af[i]  = *(const short8*)&As[(wm * 64 + i * 16 + l15) * 32 + quad * 8];
    #pragma unroll
    for (int i = 0; i < 4; i++) bfr[i] = *(const short8*)&Bs[(wn * 64 + i * 16 + l15) * 32 + quad * 8];
    #pragma unroll
    for (int mt = 0; mt < 4; mt++)
      #pragma unroll
      for (int nt = 0; nt < 4; nt++)
        acc[mt][nt] = __builtin_amdgcn_mfma_f32_16x16x32_bf16(af[mt], bfr[nt], acc[mt][nt], 0, 0, 0);
    __syncthreads();
  }

  // epilogue: each wave's 64-wide n-range is exactly one component block (q/k/v of one head)
  int g = bn * 2 + wn;          // 64-block index in n space, = 3*h + comp
  int h = g / 3, comp = g - h * 3;

  if (comp == 2){
    // V: write transposed vT[(bh*64 + d)*T + t], 4 consecutive t per lane -> ushort4
    #pragma unroll
    for (int nt = 0; nt < 4; nt++){
      int d = nt * 16 + l15;
      float bv = bias[g * 64 + d];
      #pragma unroll
      for (int mt = 0; mt < 4; mt++){
        int row = bm * 128 + wm * 64 + mt * 16 + quad * 4;
        int t = row & (T_SEQ - 1), b_ = row >> 11;
        ushort4 o;
        o.x = f2b(acc[mt][nt][0] + bv);
        o.y = f2b(acc[mt][nt][1] + bv);
        o.z = f2b(acc[mt][nt][2] + bv);
        o.w = f2b(acc[mt][nt][3] + bv);
        *(ushort4*)&vT[(size_t)((b_ * NHEADS + h) * 64 + d) * T_SEQ + t] = o;
      }
    }
  } else {
    ushort* outP = (comp == 0) ? qO : kO;
    #pragma unroll
    for (int nt = 0; nt < 4; nt++){
      int d = nt * 16 + l15;
      float bv = bias[g * 64 + d];
      float bp = bias[g * 64 + (d ^ 32)];
      int fi = d & 31;
      float sgn = (d < 32) ? -1.0f : 1.0f;
      #pragma unroll
      for (int mt = 0; mt < 4; mt++)
        #pragma unroll
        for (int r = 0; r < 4; r++){
          int row = bm * 128 + wm * 64 + mt * 16 + quad * 4 + r;
          int t = row & (T_SEQ - 1), b_ = row >> 11;
          float cv = cosT[t * 32 + fi], sv = sinT[t * 32 + fi];
          float val = acc[mt][nt][r] + bv;
          float pv  = acc[mt][nt ^ 2][r] + bp;   // element at d^32, same lane/row
          outP[(size_t)((b_ * NHEADS + h) * T_SEQ + t) * 64 + d] = f2b(val * cv + sgn * pv * sv);
        }
    }
  }
}

// ---------------- flash attention ----------------
// q,k: [B][NH][T][64] bf16 ; vT: [B][NH][64][T] bf16 ; out oB: [B][T][NH][64] bf16

__global__ __launch_bounds__(256) void attn(
    const ushort* __restrict__ qB, const ushort* __restrict__ kB,
    const ushort* __restrict__ vTB, const int* __restrict__ amask,
    ushort* __restrict__ oB)
{
  __shared__ __align__(16) ushort Ks[64][72];
  __shared__ __align__(16) ushort Vt[64][72];     // [d][key], staged from pre-transposed vT
  __shared__ __align__(16) ushort Ps[4][16][72];  // per-wave P round-trip
  int tid = threadIdx.x;
  int bh = blockIdx.x;           // b*16+h
  int qt = 31 - blockIdx.y;      // heavy q-tiles dispatched first
  int b = bh >> 4;
  int wave = tid >> 6, lane = tid & 63;
  int quad = lane >> 4, l15 = lane & 15;
  int q0 = qt * 64;

  const ushort* Qb  = qB + (size_t)bh * T_SEQ * 64;
  const ushort* Kb  = kB + (size_t)bh * T_SEQ * 64;
  const ushort* VtB = vTB + (size_t)bh * 64 * T_SEQ;

  // A-fragments of this wave's 16 q rows (held in regs for whole kernel)
  int qrow_frag = q0 + wave * 16 + l15;
  short8 qf0 = *(const short8*)&Qb[(size_t)qrow_frag * 64 + quad * 8];
  short8 qf1 = *(const short8*)&Qb[(size_t)qrow_frag * 64 + 32 + quad * 8];

  float m_i[4], l_i[4];
  floatx4 oacc[4];
  #pragma unroll
  for (int r = 0; r < 4; r++){ m_i[r] = -1e30f; l_i[r] = 0.f; }
  #pragma unroll
  for (int nt = 0; nt < 4; nt++) oacc[nt] = fzero4();

  int nkb = qt + 1;  // causal: key blocks 0..qt
  for (int kb = 0; kb < nkb; ++kb){
    int k0 = kb * 64;
    // stage K [key][d] and Vt [d][key] — both plain coalesced vector copies
    #pragma unroll
    for (int i = 0; i < 2; i++){
      int idx = tid + i * 256;
      int row = idx >> 3, c8 = (idx & 7) * 8;
      *(short8*)&Ks[row][c8] = *(const short8*)&Kb[(size_t)(k0 + row) * 64 + c8];
      *(short8*)&Vt[row][c8] = *(const short8*)&VtB[(size_t)row * T_SEQ + k0 + c8];
    }
    __syncthreads();

    // S = Q K^T  (16 q rows x 64 keys per wave)
    floatx4 sacc[4];
    #pragma unroll
    for (int nt = 0; nt < 4; nt++) sacc[nt] = fzero4();
    #pragma unroll
    for (int nt = 0; nt < 4; nt++){
      short8 kf0 = *(const short8*)&Ks[nt * 16 + l15][quad * 8];
      short8 kf1 = *(const short8*)&Ks[nt * 16 + l15][32 + quad * 8];
      sacc[nt] = __builtin_amdgcn_mfma_f32_16x16x32_bf16(qf0, kf0, sacc[nt], 0, 0, 0);
      sacc[nt] = __builtin_amdgcn_mfma_f32_16x16x32_bf16(qf1, kf1, sacc[nt], 0, 0, 0);
    }

    // mask + scale ; C-layout: row=quad*4+r, col=l15 (per 16-col tile nt)
    float p[4][4];
    float rmax[4];
    #pragma unroll
    for (int r = 0; r < 4; r++) rmax[r] = -1e30f;
    int padv[4];
    #pragma unroll
    for (int nt = 0; nt < 4; nt++) padv[nt] = amask[b * T_SEQ + k0 + nt * 16 + l15];
    #pragma unroll
    for (int nt = 0; nt < 4; nt++){
      int key = k0 + nt * 16 + l15;
      #pragma unroll
      for (int r = 0; r < 4; r++){
        int qq = q0 + wave * 16 + quad * 4 + r;
        float s = (key <= qq && padv[nt] != 0) ? sacc[nt][r] * 0.125f : -1e30f;
        p[nt][r] = s;
        rmax[r] = fmaxf(rmax[r], s);
      }
    }
    // row max across the 16 lanes of the quad
    #pragma unroll
    for (int r = 0; r < 4; r++){
      float v = rmax[r];
      v = fmaxf(v, __shfl_xor(v, 1));
      v = fmaxf(v, __shfl_xor(v, 2));
      v = fmaxf(v, __shfl_xor(v, 4));
      v = fmaxf(v, __shfl_xor(v, 8));
      rmax[r] = v;
    }
    float alpha[4], rsum[4];
    #pragma unroll
    for (int r = 0; r < 4; r++){
      float mnew = fmaxf(m_i[r], rmax[r]);
      alpha[r] = __expf(m_i[r] - mnew);
      m_i[r] = mnew;
      rsum[r] = 0.f;
    }
    #pragma unroll
    for (int nt = 0; nt < 4; nt++)
      #pragma unroll
      for (int r = 0; r < 4; r++){
        float e = __expf(p[nt][r] - m_i[r]);
        p[nt][r] = e;
        rsum[r] += e;
      }
    #pragma unroll
    for (int r = 0; r < 4; r++){
      float v = rsum[r];
      v += __shfl_xor(v, 1); v += __shfl_xor(v, 2);
      v += __shfl_xor(v, 4); v += __shfl_xor(v, 8);
      l_i[r] = l_i[r] * alpha[r] + v;
    }
    #pragma unroll
    for (int nt = 0; nt < 4; nt++)
      #pragma unroll
      for (int r = 0; r < 4; r++)
        oacc[nt][r] *= alpha[r];

    // P: C-layout -> A-layout via per-wave LDS
    #pragma unroll
    for (int nt = 0; nt < 4; nt++)
      #pragma unroll
      for (int r = 0; r < 4; r++)
        Ps[wave][quad * 4 + r][nt * 16 + l15] = f2b(p[nt][r]);
    __syncthreads();  // also guarantees Ps visibility

    short8 pa0 = *(const short8*)&Ps[wave][l15][quad * 8];
    short8 pa1 = *(const short8*)&Ps[wave][l15][32 + quad * 8];
    #pragma unroll
    for (int nt = 0; nt < 4; nt++){
      short8 vf0 = *(const short8*)&Vt[nt * 16 + l15][quad * 8];
      short8 vf1 = *(const short8*)&Vt[nt * 16 + l15][32 + quad * 8];
      oacc[nt] = __builtin_amdgcn_mfma_f32_16x16x32_bf16(pa0, vf0, oacc[nt], 0, 0, 0);
      oacc[nt] = __builtin_amdgcn_mfma_f32_16x16x32_bf16(pa1, vf1, oacc[nt], 0, 0, 0);
    }
    __syncthreads();  // before next stage overwrites Ks/Vt
  }

  // write O: [b][t][h][d]
  int h = bh & 15;
  #pragma unroll
  for (int nt = 0; nt < 4; nt++){
    int d = nt * 16 + l15;
    #pragma unroll
    for (int r = 0; r < 4; r++){
      int t = q0 + wave * 16 + quad * 4 + r;
      float o = oacc[nt][r] / l_i[r];
      oB[(size_t)((b * T_SEQ + t) * NHEADS + h) * 64 + d] = f2b(o);
    }
  }
}

// ---------------- GEMM3: out = O @ w_out (f32 out) ----------------

__global__ __launch_bounds__(256) void gemm_out_k(
    const ushort* __restrict__ A, const ushort* __restrict__ Bt,
    float* __restrict__ out)
{
  __shared__ __align__(16) ushort As[128 * 32];
  __shared__ __align__(16) ushort Bs[128 * 32];
  int tid = threadIdx.x;
  int bm = blockIdx.x, bn = blockIdx.y;
  int wave = tid >> 6, lane = tid & 63;
  int wm = wave >> 1, wn = wave & 1;
  int quad = lane >> 4, l15 = lane & 15;

  int srow0 = wave * 32 + (lane >> 2);
  int scol  = (lane & 3) * 8;
  ushort* ldsA0 = &As[wave * 1024];
  ushort* ldsA1 = &As[wave * 1024 + 512];
  ushort* ldsB0 = &Bs[wave * 1024];
  ushort* ldsB1 = &Bs[wave * 1024 + 512];

  floatx4 acc[4][4];
  for (int i = 0; i < 4; i++) for (int j = 0; j < 4; j++) acc[i][j] = fzero4();

  for (int kt = 0; kt < 32; ++kt){
    const ushort* gA = &A[(size_t)(bm * 128 + srow0) * 1024 + kt * 32 + scol];
    const ushort* gB = &Bt[(size_t)(bn * 128 + srow0) * 1024 + kt * 32 + scol];
    gl_lds16(gA, ldsA0);
    gl_lds16(gA + 16 * 1024, ldsA1);
    gl_lds16(gB, ldsB0);
    gl_lds16(gB + 16 * 1024, ldsB1);
    __syncthreads();
    short8 af[4], bfr[4];
    #pragma unroll
    for (int i = 0; i < 4; i++) af[i]  = *(const short8*)&As[(wm * 64 + i * 16 + l15) * 32 + quad * 8];
    #pragma unroll
    for (int i = 0; i < 4; i++) bfr[i] = *(const short8*)&Bs[(wn * 64 + i * 16 + l15) * 32 + quad * 8];
    #pragma unroll
    for (int mt = 0; mt < 4; mt++)
      #pragma unroll
      for (int nt = 0; nt < 4; nt++)
        acc[mt][nt] = __builtin_amdgcn_mfma_f32_16x16x32_bf16(af[mt], bfr[nt], acc[mt][nt], 0, 0, 0);
    __syncthreads();
  }

  #pragma unroll
  for (int nt = 0; nt < 4; nt++){
    int n = bn * 128 + wn * 64 + nt * 16 + l15;
    #pragma unroll
    for (int mt = 0; mt < 4; mt++)
      #pragma unroll
      for (int r = 0; r < 4; r++){
        int row = bm * 128 + wm * 64 + mt * 16 + quad * 4 + r;
        out[(size_t)row * 1024 + n] = acc[mt][nt][r];
      }
  }
}

// ---------------- launch ----------------

extern "C" void kernel_launch(void* const* d_in, const int* in_sizes, int n_in,
                              void* d_out, int out_size, void* d_ws, size_t ws_size,
                              hipStream_t stream)
{
  const float* hidden = (const float*)d_in[0];   // [2][2048][1024] f32
  const int*   amask  = (const int*)d_in[1];     // [2][2048] i32
  const float* w_qkv  = (const float*)d_in[2];   // [1024][3072] f32
  const float* b_qkv  = (const float*)d_in[3];   // [3072] f32
  const float* w_out  = (const float*)d_in[4];   // [1024][1024] f32
  float* out = (float*)d_out;

  char* ws = (char*)d_ws;
  ushort* hO    = (ushort*)(ws);                 // 8 MB: hidden bf16, later reused as attn output O
  ushort* wqkvT = (ushort*)(ws + 8388608);       // 6 MB
  ushort* woutT = (ushort*)(ws + 14680064);      // 2 MB
  ushort* qB    = (ushort*)(ws + 16777216);      // 8 MB
  ushort* kB    = (ushort*)(ws + 25165824);      // 8 MB
  ushort* vT    = (ushort*)(ws + 33554432);      // 8 MB (transposed V)
  float*  cosT  = (float*)(ws + 41943040);       // 256 KB
  float*  sinT  = (float*)(ws + 42205184);       // 256 KB

  cvt_f32_bf16<<<4096, 256, 0, stream>>>(hidden, hO, 1048576);
  transpose_cvt<<<dim3(96, 32), 256, 0, stream>>>(w_qkv, wqkvT, 1024, 3072);
  transpose_cvt<<<dim3(32, 32), 256, 0, stream>>>(w_out, woutT, 1024, 1024);
  rope_tables<<<256, 256, 0, stream>>>(cosT, sinT);
  gemm_qkv<<<dim3(32, 24), 256, 0, stream>>>(hO, wqkvT, b_qkv, qB, kB, vT, cosT, sinT);
  attn<<<dim3(32, 32), 256, 0, stream>>>(qB, kB, vT, amask, hO /* reused as O */);
  gemm_out_k<<<dim3(32, 8), 256, 0, stream>>>(hO, woutT, out);
}

// Round 3
// 226.695 us; speedup vs baseline: 1.3309x; 1.1023x over previous
//
#include <hip/hip_runtime.h>
#include <math.h>

typedef __attribute__((ext_vector_type(8))) short short8;
typedef __attribute__((ext_vector_type(4))) short short4v;
typedef __attribute__((ext_vector_type(4))) float floatx4;

#define T_SEQ 2048
#define NHEADS 16
#define HID 1024

#if __has_builtin(__builtin_amdgcn_mfma_f32_16x16x16bf16_1k)
#define HAVE_MFMA16 1
#define MFMA16(a,b,c) __builtin_amdgcn_mfma_f32_16x16x16bf16_1k(a,b,c,0,0,0)
#elif __has_builtin(__builtin_amdgcn_mfma_f32_16x16x16_bf16)
#define HAVE_MFMA16 1
#define MFMA16(a,b,c) __builtin_amdgcn_mfma_f32_16x16x16_bf16(a,b,c,0,0,0)
#else
#define HAVE_MFMA16 0
#endif

__device__ __forceinline__ ushort f2b(float x){
  union { float f; unsigned u; } c; c.f = x;
  unsigned r = c.u + 0x7fffu + ((c.u >> 16) & 1u);
  return (ushort)(r >> 16);
}

__device__ __forceinline__ floatx4 fzero4(){
  floatx4 v; v[0]=0.f; v[1]=0.f; v[2]=0.f; v[3]=0.f; return v;
}

// async global->LDS, 16B per lane, LDS dest = uniform base + lane*16
__device__ __forceinline__ void gl_lds16(const ushort* g, ushort* l){
  __builtin_amdgcn_global_load_lds(
      (const __attribute__((address_space(1))) void*)g,
      (__attribute__((address_space(3))) void*)l, 16, 0, 0);
}

// ---------------- prep kernels ----------------

__global__ void cvt_f32_bf16(const float* __restrict__ in, ushort* __restrict__ out, int n4){
  int i = blockIdx.x * 256 + threadIdx.x;
  if (i < n4){
    float4 v = ((const float4*)in)[i];
    ushort4 o;
    o.x = f2b(v.x); o.y = f2b(v.y); o.z = f2b(v.z); o.w = f2b(v.w);
    ((ushort4*)out)[i] = o;
  }
}

// in: f32 [R][C]  ->  out: bf16 [C][R]
__global__ void transpose_cvt(const float* __restrict__ in, ushort* __restrict__ out, int R, int C){
  __shared__ float tile[32][33];
  int c0 = blockIdx.x * 32, r0 = blockIdx.y * 32;
  int tx = threadIdx.x & 31, ty = threadIdx.x >> 5;
  #pragma unroll
  for (int i = 0; i < 4; i++){
    int r = ty + i * 8;
    tile[r][tx] = in[(size_t)(r0 + r) * C + c0 + tx];
  }
  __syncthreads();
  #pragma unroll
  for (int i = 0; i < 4; i++){
    int r = ty + i * 8;
    out[(size_t)(c0 + r) * R + r0 + tx] = f2b(tile[tx][r]);
  }
}

__global__ void rope_tables(float* __restrict__ cosT, float* __restrict__ sinT){
  int idx = blockIdx.x * 256 + threadIdx.x;
  if (idx < T_SEQ * 32){
    int t = idx >> 5, i = idx & 31;
    float invf = powf(10000.0f, -(float)i / 32.0f);
    float a = (float)t * invf;
    cosT[idx] = cosf(a);
    sinT[idx] = sinf(a);
  }
}

// per-batch sequence length = sum(amask[b]) (mask is a prefix by construction)
__global__ void seqlens(const int* __restrict__ amask, int* __restrict__ Lb){
  __shared__ int red[256];
  int b = blockIdx.x;
  int s = 0;
  for (int i = threadIdx.x; i < T_SEQ; i += 256) s += amask[b * T_SEQ + i];
  red[threadIdx.x] = s; __syncthreads();
  for (int o = 128; o > 0; o >>= 1){
    if (threadIdx.x < o) red[threadIdx.x] += red[threadIdx.x + o];
    __syncthreads();
  }
  if (threadIdx.x == 0) Lb[b] = red[0];
}

// ---------------- GEMM1: qkv = hidden @ w_qkv + b, fused bias + RoPE + scatter ----------------
// A: [4096][1024] bf16, Bt: [3072][1024] bf16 (w_qkv transposed)
// q (pre-scaled by 1/8), k: [B][NH][T][64] bf16 ; V TRANSPOSED: vT [B][NH][64(d)][T] bf16

__global__ __launch_bounds__(256) void gemm_qkv(
    const ushort* __restrict__ A, const ushort* __restrict__ Bt,
    const float* __restrict__ bias,
    ushort* __restrict__ qO, ushort* __restrict__ kO, ushort* __restrict__ vT,
    const float* __restrict__ cosT, const float* __restrict__ sinT)
{
  __shared__ __align__(16) ushort As[128 * 32];
  __shared__ __align__(16) ushort Bs[128 * 32];
  int tid = threadIdx.x;
  int bm = blockIdx.x, bn = blockIdx.y;
  int wave = tid >> 6, lane = tid & 63;
  int wm = wave >> 1, wn = wave & 1;
  int quad = lane >> 4, l15 = lane & 15;

  int srow0 = wave * 32 + (lane >> 2);
  int scol  = (lane & 3) * 8;
  ushort* ldsA0 = &As[wave * 1024];
  ushort* ldsA1 = &As[wave * 1024 + 512];
  ushort* ldsB0 = &Bs[wave * 1024];
  ushort* ldsB1 = &Bs[wave * 1024 + 512];

  floatx4 acc[4][4];
  for (int i = 0; i < 4; i++) for (int j = 0; j < 4; j++) acc[i][j] = fzero4();

  for (int kt = 0; kt < 32; ++kt){
    const ushort* gA = &A[(size_t)(bm * 128 + srow0) * 1024 + kt * 32 + scol];
    const ushort* gB = &Bt[(size_t)(bn * 128 + srow0) * 1024 + kt * 32 + scol];
    gl_lds16(gA, ldsA0);
    gl_lds16(gA + 16 * 1024, ldsA1);
    gl_lds16(gB, ldsB0);
    gl_lds16(gB + 16 * 1024, ldsB1);
    __syncthreads();
    short8 af[4], bfr[4];
    #pragma unroll
    for (int i = 0; i < 4; i++) af[i]  = *(const short8*)&As[(wm * 64 + i * 16 + l15) * 32 + quad * 8];
    #pragma unroll
    for (int i = 0; i < 4; i++) bfr[i] = *(const short8*)&Bs[(wn * 64 + i * 16 + l15) * 32 + quad * 8];
    #pragma unroll
    for (int mt = 0; mt < 4; mt++)
      #pragma unroll
      for (int nt = 0; nt < 4; nt++)
        acc[mt][nt] = __builtin_amdgcn_mfma_f32_16x16x32_bf16(af[mt], bfr[nt], acc[mt][nt], 0, 0, 0);
    __syncthreads();
  }

  int g = bn * 2 + wn;          // 64-block index in n space, = 3*h + comp
  int h = g / 3, comp = g - h * 3;

  if (comp == 2){
    #pragma unroll
    for (int nt = 0; nt < 4; nt++){
      int d = nt * 16 + l15;
      float bv = bias[g * 64 + d];
      #pragma unroll
      for (int mt = 0; mt < 4; mt++){
        int row = bm * 128 + wm * 64 + mt * 16 + quad * 4;
        int t = row & (T_SEQ - 1), b_ = row >> 11;
        ushort4 o;
        o.x = f2b(acc[mt][nt][0] + bv);
        o.y = f2b(acc[mt][nt][1] + bv);
        o.z = f2b(acc[mt][nt][2] + bv);
        o.w = f2b(acc[mt][nt][3] + bv);
        *(ushort4*)&vT[(size_t)((b_ * NHEADS + h) * 64 + d) * T_SEQ + t] = o;
      }
    }
  } else {
    ushort* outP = (comp == 0) ? qO : kO;
    float qs = (comp == 0) ? 0.125f : 1.0f;   // fold 1/sqrt(64) into q
    #pragma unroll
    for (int nt = 0; nt < 4; nt++){
      int d = nt * 16 + l15;
      float bv = bias[g * 64 + d];
      float bp = bias[g * 64 + (d ^ 32)];
      int fi = d & 31;
      float sgn = (d < 32) ? -1.0f : 1.0f;
      #pragma unroll
      for (int mt = 0; mt < 4; mt++)
        #pragma unroll
        for (int r = 0; r < 4; r++){
          int row = bm * 128 + wm * 64 + mt * 16 + quad * 4 + r;
          int t = row & (T_SEQ - 1), b_ = row >> 11;
          float cv = cosT[t * 32 + fi], sv = sinT[t * 32 + fi];
          float val = acc[mt][nt][r] + bv;
          float pv  = acc[mt][nt ^ 2][r] + bp;
          outP[(size_t)((b_ * NHEADS + h) * T_SEQ + t) * 64 + d] = f2b((val * cv + sgn * pv * sv) * qs);
        }
    }
  }
}

// ---------------- flash attention (S^T formulation) ----------------
// q(pre-scaled),k: [B][NH][T][64] ; vT: [B][NH][64][T] ; out oB: [B][T][NH][64]

#if HAVE_MFMA16

__global__ __launch_bounds__(256) void attn(
    const ushort* __restrict__ qB, const ushort* __restrict__ kB,
    const ushort* __restrict__ vTB, const int* __restrict__ amask,
    const int* __restrict__ Lb, ushort* __restrict__ oB)
{
  __shared__ __align__(16) ushort SH[8192];   // Ks=SH[0..4095], Vt=SH[4096..8191]
  ushort* Ks = SH;
  ushort* Vt = SH + 4096;
  int tid = threadIdx.x;
  int bh = blockIdx.x;
  int qt = 31 - blockIdx.y;      // heavy q-tiles first
  int b = bh >> 4, h = bh & 15;
  int wave = tid >> 6, lane = tid & 63;
  int quad = lane >> 4, l15 = lane & 15;
  int q0 = qt * 64;
  int L = Lb[b];

  const ushort* Qb  = qB + (size_t)bh * T_SEQ * 64;
  const ushort* Kb  = kB + (size_t)bh * T_SEQ * 64;
  const ushort* VtB = vTB + (size_t)bh * 64 * T_SEQ;

  int qrow = q0 + wave * 16 + l15;           // this lane's q (column of S^T)
  short8 qf0 = *(const short8*)&Qb[(size_t)qrow * 64 + quad * 8];
  short8 qf1 = *(const short8*)&Qb[(size_t)qrow * 64 + 32 + quad * 8];

  // staging geometry (XOR swizzle via global-source permutation)
  int lr = lane >> 3, ch = lane & 7;
  int sw = (ch ^ lr) * 8;                     // ushort offset of permuted 16B chunk
  int l7 = l15 & 7;

  float m_i = -1e30f, l_i = 0.f;
  floatx4 oacc[4];
  #pragma unroll
  for (int nt = 0; nt < 4; nt++) oacc[nt] = fzero4();

  int lastkb = qt;
  int lkb2 = (L - 1) >> 6;
  if (lkb2 < lastkb) lastkb = lkb2;          // skip fully-padded key blocks

  for (int kb = 0; kb <= lastkb; ++kb){
    int k0 = kb * 64;
    // stage K [key][d] (8KB contiguous) and V^T [d][key], swizzled
    {
      const ushort* gK = &Kb[(size_t)(k0 + wave * 16 + lr) * 64 + sw];
      gl_lds16(gK,            &Ks[(wave * 16) * 64]);
      gl_lds16(gK + 8 * 64,   &Ks[(wave * 16 + 8) * 64]);
      const ushort* gV = &VtB[(size_t)(wave * 16 + lr) * T_SEQ + k0 + sw];
      gl_lds16(gV,                &Vt[(wave * 16) * 64]);
      gl_lds16(gV + 8 * T_SEQ,    &Vt[(wave * 16 + 8) * 64]);
    }
    __syncthreads();

    // S^T = K·Q^T : 4 key-tiles of 16, C[row=key quad*4+r][col=q l15]
    floatx4 sacc[4];
    #pragma unroll
    for (int e = 0; e < 4; e++){
      short8 kf0 = *(const short8*)&Ks[(e * 16 + l15) * 64 + ((quad ^ l7) * 8)];
      short8 kf1 = *(const short8*)&Ks[(e * 16 + l15) * 64 + (((quad | 4) ^ l7) * 8)];
      floatx4 z = fzero4();
      z = __builtin_amdgcn_mfma_f32_16x16x32_bf16(kf0, qf0, z, 0, 0, 0);
      z = __builtin_amdgcn_mfma_f32_16x16x32_bf16(kf1, qf1, z, 0, 0, 0);
      sacc[e] = z;
    }

    float s[4][4];
    bool needm = (kb == qt) || (k0 + 64 > L);
    if (needm){
      #pragma unroll
      for (int e = 0; e < 4; e++)
        #pragma unroll
        for (int r = 0; r < 4; r++){
          int key = k0 + e * 16 + quad * 4 + r;
          s[e][r] = (key <= qrow && key < L) ? sacc[e][r] : -1e30f;
        }
    } else {
      #pragma unroll
      for (int e = 0; e < 4; e++)
        #pragma unroll
        for (int r = 0; r < 4; r++) s[e][r] = sacc[e][r];
    }

    // per-lane online softmax (q = this lane's column)
    float mx = s[0][0];
    #pragma unroll
    for (int e = 0; e < 4; e++)
      #pragma unroll
      for (int r = 0; r < 4; r++) mx = fmaxf(mx, s[e][r]);
    mx = fmaxf(mx, __shfl_xor(mx, 16));
    mx = fmaxf(mx, __shfl_xor(mx, 32));
    float mnew = fmaxf(m_i, mx);
    float alpha = __expf(m_i - mnew);
    m_i = mnew;
    float sum = 0.f;
    #pragma unroll
    for (int e = 0; e < 4; e++)
      #pragma unroll
      for (int r = 0; r < 4; r++){
        float ev = __expf(s[e][r] - mnew);
        s[e][r] = ev;
        sum += ev;
      }
    sum += __shfl_xor(sum, 16);
    sum += __shfl_xor(sum, 32);
    l_i = l_i * alpha + sum;
    #pragma unroll
    for (int nt = 0; nt < 4; nt++)
      #pragma unroll
      for (int r = 0; r < 4; r++) oacc[nt][r] *= alpha;

    // pack P^T fragments (truncating f32->bf16): regs ARE the 16x16x16 B-operand
    short4v pf[4];
    #pragma unroll
    for (int e = 0; e < 4; e++){
      union { unsigned u[2]; short4v v; } pk;
      pk.u[0] = (__float_as_uint(s[e][1]) & 0xffff0000u) | (__float_as_uint(s[e][0]) >> 16);
      pk.u[1] = (__float_as_uint(s[e][3]) & 0xffff0000u) | (__float_as_uint(s[e][2]) >> 16);
      pf[e] = pk.v;
    }

    // O^T += V^T · P^T : A = V^T frag (m=d, k=key quad*4+j)
    #pragma unroll
    for (int nt = 0; nt < 4; nt++){
      #pragma unroll
      for (int e = 0; e < 4; e++){
        int cw = e * 2 + (quad >> 1);
        short4v vf = *(const short4v*)&Vt[(nt * 16 + l15) * 64 + ((cw ^ l7) * 8) + (quad & 1) * 4];
        oacc[nt] = MFMA16(vf, pf[e], oacc[nt]);
      }
    }
    __syncthreads();
  }

  // epilogue: O^T regs -> LDS transpose -> coalesced [b][t][h][d] stores
  float inv = 1.f / l_i;
  ushort (*Ot)[72] = (ushort(*)[72])SH;       // 64 x 72 = 4608 ushorts < 8192
  #pragma unroll
  for (int nt = 0; nt < 4; nt++){
    ushort4 o;
    o.x = f2b(oacc[nt][0] * inv);
    o.y = f2b(oacc[nt][1] * inv);
    o.z = f2b(oacc[nt][2] * inv);
    o.w = f2b(oacc[nt][3] * inv);
    *(ushort4*)&Ot[wave * 16 + l15][nt * 16 + quad * 4] = o;
  }
  __syncthreads();
  int r = tid >> 2, c = (tid & 3) * 16;
  short8 o0 = *(const short8*)&Ot[r][c];
  short8 o1 = *(const short8*)&Ot[r][c + 8];
  ushort* dst = &oB[(size_t)((b * T_SEQ + q0 + r) * NHEADS + h) * 64 + c];
  *(short8*)dst = o0;
  *(short8*)(dst + 8) = o1;
}

#else  // fallback: R2-style attn (S layout, P via LDS round-trip)

__global__ __launch_bounds__(256) void attn(
    const ushort* __restrict__ qB, const ushort* __restrict__ kB,
    const ushort* __restrict__ vTB, const int* __restrict__ amask,
    const int* __restrict__ Lb, ushort* __restrict__ oB)
{
  __shared__ __align__(16) ushort Ks[64][72];
  __shared__ __align__(16) ushort Vt[64][72];
  __shared__ __align__(16) ushort Ps[4][16][72];
  int tid = threadIdx.x;
  int bh = blockIdx.x;
  int qt = 31 - blockIdx.y;
  int b = bh >> 4;
  int wave = tid >> 6, lane = tid & 63;
  int quad = lane >> 4, l15 = lane & 15;
  int q0 = qt * 64;

  const ushort* Qb  = qB + (size_t)bh * T_SEQ * 64;
  const ushort* Kb  = kB + (size_t)bh * T_SEQ * 64;
  const ushort* VtB = vTB + (size_t)bh * 64 * T_SEQ;

  int qrow_frag = q0 + wave * 16 + l15;
  short8 qf0 = *(const short8*)&Qb[(size_t)qrow_frag * 64 + quad * 8];
  short8 qf1 = *(const short8*)&Qb[(size_t)qrow_frag * 64 + 32 + quad * 8];

  float m_i[4], l_i[4];
  floatx4 oacc[4];
  #pragma unroll
  for (int r = 0; r < 4; r++){ m_i[r] = -1e30f; l_i[r] = 0.f; }
  #pragma unroll
  for (int nt = 0; nt < 4; nt++) oacc[nt] = fzero4();

  int nkb = qt + 1;
  for (int kb = 0; kb < nkb; ++kb){
    int k0 = kb * 64;
    #pragma unroll
    for (int i = 0; i < 2; i++){
      int idx = tid + i * 256;
      int row = idx >> 3, c8 = (idx & 7) * 8;
      *(short8*)&Ks[row][c8] = *(const short8*)&Kb[(size_t)(k0 + row) * 64 + c8];
      *(short8*)&Vt[row][c8] = *(const short8*)&VtB[(size_t)row * T_SEQ + k0 + c8];
    }
    __syncthreads();

    floatx4 sacc[4];
    #pragma unroll
    for (int nt = 0; nt < 4; nt++) sacc[nt] = fzero4();
    #pragma unroll
    for (int nt = 0; nt < 4; nt++){
      short8 kf0 = *(const short8*)&Ks[nt * 16 + l15][quad * 8];
      short8 kf1 = *(const short8*)&Ks[nt * 16 + l15][32 + quad * 8];
      sacc[nt] = __builtin_amdgcn_mfma_f32_16x16x32_bf16(qf0, kf0, sacc[nt], 0, 0, 0);
      sacc[nt] = __builtin_amdgcn_mfma_f32_16x16x32_bf16(qf1, kf1, sacc[nt], 0, 0, 0);
    }

    float p[4][4];
    float rmax[4];
    #pragma unroll
    for (int r = 0; r < 4; r++) rmax[r] = -1e30f;
    int padv[4];
    #pragma unroll
    for (int nt = 0; nt < 4; nt++) padv[nt] = amask[b * T_SEQ + k0 + nt * 16 + l15];
    #pragma unroll
    for (int nt = 0; nt < 4; nt++){
      int key = k0 + nt * 16 + l15;
      #pragma unroll
      for (int r = 0; r < 4; r++){
        int qq = q0 + wave * 16 + quad * 4 + r;
        float sv = (key <= qq && padv[nt] != 0) ? sacc[nt][r] : -1e30f;
        p[nt][r] = sv;
        rmax[r] = fmaxf(rmax[r], sv);
      }
    }
    #pragma unroll
    for (int r = 0; r < 4; r++){
      float v = rmax[r];
      v = fmaxf(v, __shfl_xor(v, 1));
      v = fmaxf(v, __shfl_xor(v, 2));
      v = fmaxf(v, __shfl_xor(v, 4));
      v = fmaxf(v, __shfl_xor(v, 8));
      rmax[r] = v;
    }
    float alpha[4], rsum[4];
    #pragma unroll
    for (int r = 0; r < 4; r++){
      float mnew = fmaxf(m_i[r], rmax[r]);
      alpha[r] = __expf(m_i[r] - mnew);
      m_i[r] = mnew;
      rsum[r] = 0.f;
    }
    #pragma unroll
    for (int nt = 0; nt < 4; nt++)
      #pragma unroll
      for (int r = 0; r < 4; r++){
        float e = __expf(p[nt][r] - m_i[r]);
        p[nt][r] = e;
        rsum[r] += e;
      }
    #pragma unroll
    for (int r = 0; r < 4; r++){
      float v = rsum[r];
      v += __shfl_xor(v, 1); v += __shfl_xor(v, 2);
      v += __shfl_xor(v, 4); v += __shfl_xor(v, 8);
      l_i[r] = l_i[r] * alpha[r] + v;
    }
    #pragma unroll
    for (int nt = 0; nt < 4; nt++)
      #pragma unroll
      for (int r = 0; r < 4; r++)
        oacc[nt][r] *= alpha[r];

    #pragma unroll
    for (int nt = 0; nt < 4; nt++)
      #pragma unroll
      for (int r = 0; r < 4; r++)
        Ps[wave][quad * 4 + r][nt * 16 + l15] = f2b(p[nt][r]);
    __syncthreads();

    short8 pa0 = *(const short8*)&Ps[wave][l15][quad * 8];
    short8 pa1 = *(const short8*)&Ps[wave][l15][32 + quad * 8];
    #pragma unroll
    for (int nt = 0; nt < 4; nt++){
      short8 vf0 = *(const short8*)&Vt[nt * 16 + l15][quad * 8];
      short8 vf1 = *(const short8*)&Vt[nt * 16 + l15][32 + quad * 8];
      oacc[nt] = __builtin_amdgcn_mfma_f32_16x16x32_bf16(pa0, vf0, oacc[nt], 0, 0, 0);
      oacc[nt] = __builtin_amdgcn_mfma_f32_16x16x32_bf16(pa1, vf1, oacc[nt], 0, 0, 0);
    }
    __syncthreads();
  }

  int h = bh & 15;
  #pragma unroll
  for (int nt = 0; nt < 4; nt++){
    int d = nt * 16 + l15;
    #pragma unroll
    for (int r = 0; r < 4; r++){
      int t = q0 + wave * 16 + quad * 4 + r;
      float o = oacc[nt][r] / l_i[r];
      oB[(size_t)((b * T_SEQ + t) * NHEADS + h) * 64 + d] = f2b(o);
    }
  }
}

#endif

// ---------------- GEMM3: out = O @ w_out (f32 out) ----------------

__global__ __launch_bounds__(256) void gemm_out_k(
    const ushort* __restrict__ A, const ushort* __restrict__ Bt,
    float* __restrict__ out)
{
  __shared__ __align__(16) ushort As[128 * 32];
  __shared__ __align__(16) ushort Bs[128 * 32];
  int tid = threadIdx.x;
  int bm = blockIdx.x, bn = blockIdx.y;
  int wave = tid >> 6, lane = tid & 63;
  int wm = wave >> 1, wn = wave & 1;
  int quad = lane >> 4, l15 = lane & 15;

  int srow0 = wave * 32 + (lane >> 2);
  int scol  = (lane & 3) * 8;
  ushort* ldsA0 = &As[wave * 1024];
  ushort* ldsA1 = &As[wave * 1024 + 512];
  ushort* ldsB0 = &Bs[wave * 1024];
  ushort* ldsB1 = &Bs[wave * 1024 + 512];

  floatx4 acc[4][4];
  for (int i = 0; i < 4; i++) for (int j = 0; j < 4; j++) acc[i][j] = fzero4();

  for (int kt = 0; kt < 32; ++kt){
    const ushort* gA = &A[(size_t)(bm * 128 + srow0) * 1024 + kt * 32 + scol];
    const ushort* gB = &Bt[(size_t)(bn * 128 + srow0) * 1024 + kt * 32 + scol];
    gl_lds16(gA, ldsA0);
    gl_lds16(gA + 16 * 1024, ldsA1);
    gl_lds16(gB, ldsB0);
    gl_lds16(gB + 16 * 1024, ldsB1);
    __syncthreads();
    short8 af[4], bfr[4];
    #pragma unroll
    for (int i = 0; i < 4; i++) af[i]  = *(const short8*)&As[(wm * 64 + i * 16 + l15) * 32 + quad * 8];
    #pragma unroll
    for (int i = 0; i < 4; i++) bfr[i] = *(const short8*)&Bs[(wn * 64 + i * 16 + l15) * 32 + quad * 8];
    #pragma unroll
    for (int mt = 0; mt < 4; mt++)
      #pragma unroll
      for (int nt = 0; nt < 4; nt++)
        acc[mt][nt] = __builtin_amdgcn_mfma_f32_16x16x32_bf16(af[mt], bfr[nt], acc[mt][nt], 0, 0, 0);
    __syncthreads();
  }

  #pragma unroll
  for (int nt = 0; nt < 4; nt++){
    int n = bn * 128 + wn * 64 + nt * 16 + l15;
    #pragma unroll
    for (int mt = 0; mt < 4; mt++)
      #pragma unroll
      for (int r = 0; r < 4; r++){
        int row = bm * 128 + wm * 64 + mt * 16 + quad * 4 + r;
        out[(size_t)row * 1024 + n] = acc[mt][nt][r];
      }
  }
}

// ---------------- launch ----------------

extern "C" void kernel_launch(void* const* d_in, const int* in_sizes, int n_in,
                              void* d_out, int out_size, void* d_ws, size_t ws_size,
                              hipStream_t stream)
{
  const float* hidden = (const float*)d_in[0];
  const int*   amask  = (const int*)d_in[1];
  const float* w_qkv  = (const float*)d_in[2];
  const float* b_qkv  = (const float*)d_in[3];
  const float* w_out  = (const float*)d_in[4];
  float* out = (float*)d_out;

  char* ws = (char*)d_ws;
  ushort* hO    = (ushort*)(ws);                 // 8 MB: hidden bf16, later reused as attn output O
  ushort* wqkvT = (ushort*)(ws + 8388608);       // 6 MB
  ushort* woutT = (ushort*)(ws + 14680064);      // 2 MB
  ushort* qB    = (ushort*)(ws + 16777216);      // 8 MB
  ushort* kB    = (ushort*)(ws + 25165824);      // 8 MB
  ushort* vT    = (ushort*)(ws + 33554432);      // 8 MB (transposed V)
  float*  cosT  = (float*)(ws + 41943040);       // 256 KB
  float*  sinT  = (float*)(ws + 42205184);       // 256 KB
  int*    Lb    = (int*)(ws + 42467328);         // 8 B

  cvt_f32_bf16<<<4096, 256, 0, stream>>>(hidden, hO, 1048576);
  transpose_cvt<<<dim3(96, 32), 256, 0, stream>>>(w_qkv, wqkvT, 1024, 3072);
  transpose_cvt<<<dim3(32, 32), 256, 0, stream>>>(w_out, woutT, 1024, 1024);
  rope_tables<<<256, 256, 0, stream>>>(cosT, sinT);
  seqlens<<<2, 256, 0, stream>>>(amask, Lb);
  gemm_qkv<<<dim3(32, 24), 256, 0, stream>>>(hO, wqkvT, b_qkv, qB, kB, vT, cosT, sinT);
  attn<<<dim3(32, 32), 256, 0, stream>>>(qB, kB, vT, amask, Lb, hO /* reused as O */);
  gemm_out_k<<<dim3(32, 8), 256, 0, stream>>>(hO, woutT, out);
}

// Round 5
// 195.357 us; speedup vs baseline: 1.5444x; 1.1604x over previous
//
#include <hip/hip_runtime.h>
#include <math.h>

typedef __attribute__((ext_vector_type(8))) short short8;
typedef __attribute__((ext_vector_type(4))) short short4v;
typedef __attribute__((ext_vector_type(4))) float floatx4;

#define T_SEQ 2048
#define NHEADS 16
#define HID 1024

// Device pass picks a real builtin; host pass (no target builtins declared)
// picks the no-op so the kernel body still parses. Host never runs device code.
#if __has_builtin(__builtin_amdgcn_mfma_f32_16x16x16bf16_1k)
#define MFMA16(a,b,c) __builtin_amdgcn_mfma_f32_16x16x16bf16_1k(a,b,c,0,0,0)
#elif __has_builtin(__builtin_amdgcn_mfma_f32_16x16x16_bf16)
#define MFMA16(a,b,c) __builtin_amdgcn_mfma_f32_16x16x16_bf16(a,b,c,0,0,0)
#else
#define MFMA16(a,b,c) (c)
#endif

__device__ __forceinline__ ushort f2b(float x){
  union { float f; unsigned u; } c; c.f = x;
  unsigned r = c.u + 0x7fffu + ((c.u >> 16) & 1u);
  return (ushort)(r >> 16);
}

__device__ __forceinline__ floatx4 fzero4(){
  floatx4 v; v[0]=0.f; v[1]=0.f; v[2]=0.f; v[3]=0.f; return v;
}

// async global->LDS, 16B per lane, LDS dest = uniform base + lane*16
__device__ __forceinline__ void gl_lds16(const ushort* g, ushort* l){
  __builtin_amdgcn_global_load_lds(
      (const __attribute__((address_space(1))) void*)g,
      (__attribute__((address_space(3))) void*)l, 16, 0, 0);
}

// ---------------- fused prep kernel ----------------
// blocks: [0,4096)   : hidden f32 -> bf16
//         [4096,7168): transpose+cvt w_qkv (1024x3072 -> 3072x1024)
//         [7168,8192): transpose+cvt w_out (1024x1024 -> 1024x1024)
//         [8192,8448): rope cs table (float2 cos,sin)
//         [8448,8450): per-batch seqlen

__global__ __launch_bounds__(256) void prep(
    const float* __restrict__ hidden, const float* __restrict__ w_qkv,
    const float* __restrict__ w_out, const int* __restrict__ amask,
    ushort* __restrict__ hO, ushort* __restrict__ wqkvT, ushort* __restrict__ woutT,
    float2* __restrict__ cs, int* __restrict__ Lb)
{
  __shared__ __align__(16) char smem[32 * 33 * 4];
  int blk = blockIdx.x;
  int tid = threadIdx.x;

  if (blk < 4096){
    int i = blk * 256 + tid;
    float4 v = ((const float4*)hidden)[i];
    ushort4 o;
    o.x = f2b(v.x); o.y = f2b(v.y); o.z = f2b(v.z); o.w = f2b(v.w);
    ((ushort4*)hO)[i] = o;
  } else if (blk < 8192){
    const float* in; ushort* out; int R, C, bx, by;
    if (blk < 7168){
      int t = blk - 4096; bx = t % 96; by = t / 96;
      in = w_qkv; out = wqkvT; R = 1024; C = 3072;
    } else {
      int t = blk - 7168; bx = t & 31; by = t >> 5;
      in = w_out; out = woutT; R = 1024; C = 1024;
    }
    float (*tile)[33] = (float(*)[33])smem;
    int c0 = bx * 32, r0 = by * 32;
    int tx = tid & 31, ty = tid >> 5;
    #pragma unroll
    for (int i = 0; i < 4; i++){
      int r = ty + i * 8;
      tile[r][tx] = in[(size_t)(r0 + r) * C + c0 + tx];
    }
    __syncthreads();
    #pragma unroll
    for (int i = 0; i < 4; i++){
      int r = ty + i * 8;
      out[(size_t)(c0 + r) * R + r0 + tx] = f2b(tile[tx][r]);
    }
  } else if (blk < 8448){
    int idx = (blk - 8192) * 256 + tid;
    int t = idx >> 5, i = idx & 31;
    float invf = powf(10000.0f, -(float)i / 32.0f);
    float a = (float)t * invf;
    cs[idx] = make_float2(cosf(a), sinf(a));
  } else {
    int b = blk - 8448;
    int* red = (int*)smem;
    int s = 0;
    for (int i = tid; i < T_SEQ; i += 256) s += amask[b * T_SEQ + i];
    red[tid] = s; __syncthreads();
    for (int o = 128; o > 0; o >>= 1){
      if (tid < o) red[tid] += red[tid + o];
      __syncthreads();
    }
    if (tid == 0) Lb[b] = red[0];
  }
}

// ---------------- GEMM1: qkv = hidden @ w_qkv + b, fused bias + RoPE + scatter ----------------
// double-buffered LDS, one barrier per K-iteration

__global__ __launch_bounds__(256) void gemm_qkv(
    const ushort* __restrict__ A, const ushort* __restrict__ Bt,
    const float* __restrict__ bias,
    ushort* __restrict__ qO, ushort* __restrict__ kO, ushort* __restrict__ vT,
    const float2* __restrict__ cs)
{
  __shared__ __align__(16) ushort As[2][4096];
  __shared__ __align__(16) ushort Bs[2][4096];
  int tid = threadIdx.x;
  int bm = blockIdx.x, bn = blockIdx.y;
  int wave = tid >> 6, lane = tid & 63;
  int wm = wave >> 1, wn = wave & 1;
  int quad = lane >> 4, l15 = lane & 15;

  int srow0 = wave * 32 + (lane >> 2);
  int scol  = (lane & 3) * 8;
  const ushort* baseA = &A[(size_t)(bm * 128 + srow0) * 1024 + scol];
  const ushort* baseB = &Bt[(size_t)(bn * 128 + srow0) * 1024 + scol];

  floatx4 acc[4][4];
  for (int i = 0; i < 4; i++) for (int j = 0; j < 4; j++) acc[i][j] = fzero4();

  // preload kt=0
  gl_lds16(baseA,             &As[0][wave * 1024]);
  gl_lds16(baseA + 16 * 1024, &As[0][wave * 1024 + 512]);
  gl_lds16(baseB,             &Bs[0][wave * 1024]);
  gl_lds16(baseB + 16 * 1024, &Bs[0][wave * 1024 + 512]);
  __syncthreads();

  for (int kt = 0; kt < 32; ++kt){
    int cur = kt & 1;
    if (kt < 31){
      const ushort* gA = baseA + (kt + 1) * 32;
      const ushort* gB = baseB + (kt + 1) * 32;
      gl_lds16(gA,             &As[cur ^ 1][wave * 1024]);
      gl_lds16(gA + 16 * 1024, &As[cur ^ 1][wave * 1024 + 512]);
      gl_lds16(gB,             &Bs[cur ^ 1][wave * 1024]);
      gl_lds16(gB + 16 * 1024, &Bs[cur ^ 1][wave * 1024 + 512]);
    }
    short8 af[4], bfr[4];
    #pragma unroll
    for (int i = 0; i < 4; i++) af[i]  = *(const short8*)&As[cur][(wm * 64 + i * 16 + l15) * 32 + quad * 8];
    #pragma unroll
    for (int i = 0; i < 4; i++) bfr[i] = *(const short8*)&Bs[cur][(wn * 64 + i * 16 + l15) * 32 + quad * 8];
    #pragma unroll
    for (int mt = 0; mt < 4; mt++)
      #pragma unroll
      for (int nt = 0; nt < 4; nt++)
        acc[mt][nt] = __builtin_amdgcn_mfma_f32_16x16x32_bf16(af[mt], bfr[nt], acc[mt][nt], 0, 0, 0);
    __syncthreads();
  }

  int g = bn * 2 + wn;          // = 3*h + comp
  int h = g / 3, comp = g - h * 3;

  if (comp == 2){
    #pragma unroll
    for (int nt = 0; nt < 4; nt++){
      int d = nt * 16 + l15;
      float bv = bias[g * 64 + d];
      #pragma unroll
      for (int mt = 0; mt < 4; mt++){
        int row = bm * 128 + wm * 64 + mt * 16 + quad * 4;
        int t = row & (T_SEQ - 1), b_ = row >> 11;
        ushort4 o;
        o.x = f2b(acc[mt][nt][0] + bv);
        o.y = f2b(acc[mt][nt][1] + bv);
        o.z = f2b(acc[mt][nt][2] + bv);
        o.w = f2b(acc[mt][nt][3] + bv);
        *(ushort4*)&vT[(size_t)((b_ * NHEADS + h) * 64 + d) * T_SEQ + t] = o;
      }
    }
  } else {
    ushort* outP = (comp == 0) ? qO : kO;
    float qs = (comp == 0) ? 0.125f : 1.0f;   // fold 1/sqrt(64) into q
    float bv[4], bp[4];
    #pragma unroll
    for (int nt = 0; nt < 4; nt++){
      bv[nt] = bias[g * 64 + nt * 16 + l15];
      bp[nt] = bias[g * 64 + ((nt * 16 + l15) ^ 32)];
    }
    #pragma unroll
    for (int mt = 0; mt < 4; mt++)
      #pragma unroll
      for (int r = 0; r < 4; r++){
        int row = bm * 128 + wm * 64 + mt * 16 + quad * 4 + r;
        int t = row & (T_SEQ - 1), b_ = row >> 11;
        float2 c0 = cs[t * 32 + l15];        // fi for nt even
        float2 c1 = cs[t * 32 + 16 + l15];   // fi for nt odd
        size_t base = (size_t)((b_ * NHEADS + h) * T_SEQ + t) * 64 + l15;
        #pragma unroll
        for (int nt = 0; nt < 4; nt++){
          float cvv = (nt & 1) ? c1.x : c0.x;
          float svv = (nt & 1) ? c1.y : c0.y;
          float sgn = (nt < 2) ? -1.0f : 1.0f;
          float val = acc[mt][nt][r] + bv[nt];
          float pv  = acc[mt][nt ^ 2][r] + bp[nt];
          outP[base + nt * 16] = f2b((val * cvv + sgn * pv * svv) * qs);
        }
      }
  }
}

// ---------------- flash attention (S^T formulation, double-buffered) ----------------
// q(pre-scaled),k: [B][NH][T][64] ; vT: [B][NH][64][T] ; out oB: [B][T][NH][64]

__global__ __launch_bounds__(256) void attn(
    const ushort* __restrict__ qB, const ushort* __restrict__ kB,
    const ushort* __restrict__ vTB, const int* __restrict__ Lb,
    ushort* __restrict__ oB)
{
  __shared__ __align__(16) ushort SH[2][8192];   // per buf: Ks [0,4096), Vt [4096,8192)
  int tid = threadIdx.x;
  int bh = blockIdx.x;
  int qt = 31 - blockIdx.y;      // heavy q-tiles first
  int b = bh >> 4, h = bh & 15;
  int wave = tid >> 6, lane = tid & 63;
  int quad = lane >> 4, l15 = lane & 15;
  int q0 = qt * 64;
  int L = Lb[b];

  const ushort* Qb  = qB + (size_t)bh * T_SEQ * 64;
  const ushort* Kb  = kB + (size_t)bh * T_SEQ * 64;
  const ushort* VtB = vTB + (size_t)bh * 64 * T_SEQ;

  int qrow = q0 + wave * 16 + l15;           // this lane's q (column of S^T)
  short8 qf0 = *(const short8*)&Qb[(size_t)qrow * 64 + quad * 8];
  short8 qf1 = *(const short8*)&Qb[(size_t)qrow * 64 + 32 + quad * 8];

  // staging geometry (XOR swizzle via global-source permutation)
  int lr = lane >> 3, ch = lane & 7;
  int sw = (ch ^ lr) * 8;                     // ushort offset of permuted 16B chunk
  int l7 = l15 & 7;

  float m_i = -1e30f, l_i = 0.f;
  floatx4 oacc[4];
  #pragma unroll
  for (int nt = 0; nt < 4; nt++) oacc[nt] = fzero4();

  int lastkb = qt;
  int lkb2 = (L - 1) >> 6;
  if (lkb2 < lastkb) lastkb = lkb2;          // skip fully-padded key blocks

  auto stageKV = [&](int kb, int buf){
    int k0 = kb * 64;
    const ushort* gK = &Kb[(size_t)(k0 + wave * 16 + lr) * 64 + sw];
    gl_lds16(gK,          &SH[buf][(wave * 16) * 64]);
    gl_lds16(gK + 8 * 64, &SH[buf][(wave * 16 + 8) * 64]);
    const ushort* gV = &VtB[(size_t)(wave * 16 + lr) * T_SEQ + k0 + sw];
    gl_lds16(gV,             &SH[buf][4096 + (wave * 16) * 64]);
    gl_lds16(gV + 8 * T_SEQ, &SH[buf][4096 + (wave * 16 + 8) * 64]);
  };

  stageKV(0, 0);
  __syncthreads();

  for (int kb = 0; kb <= lastkb; ++kb){
    int cur = kb & 1;
    if (kb < lastkb) stageKV(kb + 1, cur ^ 1);
    const ushort* Ks = &SH[cur][0];
    const ushort* Vt = &SH[cur][4096];
    int k0 = kb * 64;

    // S^T = K·Q^T : 4 key-tiles of 16, C[row=key quad*4+r][col=q l15]
    floatx4 sacc[4];
    #pragma unroll
    for (int e = 0; e < 4; e++){
      short8 kf0 = *(const short8*)&Ks[(e * 16 + l15) * 64 + ((quad ^ l7) * 8)];
      short8 kf1 = *(const short8*)&Ks[(e * 16 + l15) * 64 + (((quad | 4) ^ l7) * 8)];
      floatx4 z = fzero4();
      z = __builtin_amdgcn_mfma_f32_16x16x32_bf16(kf0, qf0, z, 0, 0, 0);
      z = __builtin_amdgcn_mfma_f32_16x16x32_bf16(kf1, qf1, z, 0, 0, 0);
      sacc[e] = z;
    }

    float s[4][4];
    bool needm = (kb == qt) || (k0 + 64 > L);
    if (needm){
      #pragma unroll
      for (int e = 0; e < 4; e++)
        #pragma unroll
        for (int r = 0; r < 4; r++){
          int key = k0 + e * 16 + quad * 4 + r;
          s[e][r] = (key <= qrow && key < L) ? sacc[e][r] : -1e30f;
        }
    } else {
      #pragma unroll
      for (int e = 0; e < 4; e++)
        #pragma unroll
        for (int r = 0; r < 4; r++) s[e][r] = sacc[e][r];
    }

    // per-lane online softmax (q = this lane's column)
    float mx = s[0][0];
    #pragma unroll
    for (int e = 0; e < 4; e++)
      #pragma unroll
      for (int r = 0; r < 4; r++) mx = fmaxf(mx, s[e][r]);
    mx = fmaxf(mx, __shfl_xor(mx, 16));
    mx = fmaxf(mx, __shfl_xor(mx, 32));
    float mnew = fmaxf(m_i, mx);
    float alpha = __expf(m_i - mnew);
    m_i = mnew;
    float sum = 0.f;
    #pragma unroll
    for (int e = 0; e < 4; e++)
      #pragma unroll
      for (int r = 0; r < 4; r++){
        float ev = __expf(s[e][r] - mnew);
        s[e][r] = ev;
        sum += ev;
      }
    sum += __shfl_xor(sum, 16);
    sum += __shfl_xor(sum, 32);
    l_i = l_i * alpha + sum;
    #pragma unroll
    for (int nt = 0; nt < 4; nt++)
      #pragma unroll
      for (int r = 0; r < 4; r++) oacc[nt][r] *= alpha;

    // pack P^T fragments: regs ARE the 16x16x16 B-operand
    short4v pf[4];
    #pragma unroll
    for (int e = 0; e < 4; e++){
      union { unsigned u[2]; short4v v; } pk;
      pk.u[0] = (__float_as_uint(s[e][1]) & 0xffff0000u) | (__float_as_uint(s[e][0]) >> 16);
      pk.u[1] = (__float_as_uint(s[e][3]) & 0xffff0000u) | (__float_as_uint(s[e][2]) >> 16);
      pf[e] = pk.v;
    }

    // O^T += V^T · P^T : A = V^T frag (m=d, k=key quad*4+j)
    #pragma unroll
    for (int nt = 0; nt < 4; nt++){
      #pragma unroll
      for (int e = 0; e < 4; e++){
        int cw = e * 2 + (quad >> 1);
        short4v vf = *(const short4v*)&Vt[(nt * 16 + l15) * 64 + ((cw ^ l7) * 8) + (quad & 1) * 4];
        oacc[nt] = MFMA16(vf, pf[e], oacc[nt]);
      }
    }
    __syncthreads();
  }

  // epilogue: O^T regs -> LDS transpose -> coalesced [b][t][h][d] stores
  float inv = 1.f / l_i;
  ushort (*Ot)[80] = (ushort(*)[80])&SH[0][0];   // 64 x 80 (16B-aligned rows)
  #pragma unroll
  for (int nt = 0; nt < 4; nt++){
    ushort4 o;
    o.x = f2b(oacc[nt][0] * inv);
    o.y = f2b(oacc[nt][1] * inv);
    o.z = f2b(oacc[nt][2] * inv);
    o.w = f2b(oacc[nt][3] * inv);
    *(ushort4*)&Ot[wave * 16 + l15][nt * 16 + quad * 4] = o;
  }
  __syncthreads();
  int r = tid >> 2, c = (tid & 3) * 16;
  short8 o0 = *(const short8*)&Ot[r][c];
  short8 o1 = *(const short8*)&Ot[r][c + 8];
  ushort* dst = &oB[(size_t)((b * T_SEQ + q0 + r) * NHEADS + h) * 64 + c];
  *(short8*)dst = o0;
  *(short8*)(dst + 8) = o1;
}

// ---------------- GEMM3: out = O @ w_out (f32 out), double-buffered ----------------

__global__ __launch_bounds__(256) void gemm_out_k(
    const ushort* __restrict__ A, const ushort* __restrict__ Bt,
    float* __restrict__ out)
{
  __shared__ __align__(16) ushort As[2][4096];
  __shared__ __align__(16) ushort Bs[2][4096];
  int tid = threadIdx.x;
  int bm = blockIdx.x, bn = blockIdx.y;
  int wave = tid >> 6, lane = tid & 63;
  int wm = wave >> 1, wn = wave & 1;
  int quad = lane >> 4, l15 = lane & 15;

  int srow0 = wave * 32 + (lane >> 2);
  int scol  = (lane & 3) * 8;
  const ushort* baseA = &A[(size_t)(bm * 128 + srow0) * 1024 + scol];
  const ushort* baseB = &Bt[(size_t)(bn * 128 + srow0) * 1024 + scol];

  floatx4 acc[4][4];
  for (int i = 0; i < 4; i++) for (int j = 0; j < 4; j++) acc[i][j] = fzero4();

  gl_lds16(baseA,             &As[0][wave * 1024]);
  gl_lds16(baseA + 16 * 1024, &As[0][wave * 1024 + 512]);
  gl_lds16(baseB,             &Bs[0][wave * 1024]);
  gl_lds16(baseB + 16 * 1024, &Bs[0][wave * 1024 + 512]);
  __syncthreads();

  for (int kt = 0; kt < 32; ++kt){
    int cur = kt & 1;
    if (kt < 31){
      const ushort* gA = baseA + (kt + 1) * 32;
      const ushort* gB = baseB + (kt + 1) * 32;
      gl_lds16(gA,             &As[cur ^ 1][wave * 1024]);
      gl_lds16(gA + 16 * 1024, &As[cur ^ 1][wave * 1024 + 512]);
      gl_lds16(gB,             &Bs[cur ^ 1][wave * 1024]);
      gl_lds16(gB + 16 * 1024, &Bs[cur ^ 1][wave * 1024 + 512]);
    }
    short8 af[4], bfr[4];
    #pragma unroll
    for (int i = 0; i < 4; i++) af[i]  = *(const short8*)&As[cur][(wm * 64 + i * 16 + l15) * 32 + quad * 8];
    #pragma unroll
    for (int i = 0; i < 4; i++) bfr[i] = *(const short8*)&Bs[cur][(wn * 64 + i * 16 + l15) * 32 + quad * 8];
    #pragma unroll
    for (int mt = 0; mt < 4; mt++)
      #pragma unroll
      for (int nt = 0; nt < 4; nt++)
        acc[mt][nt] = __builtin_amdgcn_mfma_f32_16x16x32_bf16(af[mt], bfr[nt], acc[mt][nt], 0, 0, 0);
    __syncthreads();
  }

  #pragma unroll
  for (int nt = 0; nt < 4; nt++){
    int n = bn * 128 + wn * 64 + nt * 16 + l15;
    #pragma unroll
    for (int mt = 0; mt < 4; mt++)
      #pragma unroll
      for (int r = 0; r < 4; r++){
        int row = bm * 128 + wm * 64 + mt * 16 + quad * 4 + r;
        out[(size_t)row * 1024 + n] = acc[mt][nt][r];
      }
  }
}

// ---------------- launch ----------------

extern "C" void kernel_launch(void* const* d_in, const int* in_sizes, int n_in,
                              void* d_out, int out_size, void* d_ws, size_t ws_size,
                              hipStream_t stream)
{
  const float* hidden = (const float*)d_in[0];
  const int*   amask  = (const int*)d_in[1];
  const float* w_qkv  = (const float*)d_in[2];
  const float* b_qkv  = (const float*)d_in[3];
  const float* w_out  = (const float*)d_in[4];
  float* out = (float*)d_out;

  char* ws = (char*)d_ws;
  ushort* hO    = (ushort*)(ws);                 // 8 MB: hidden bf16, later reused as attn output O
  ushort* wqkvT = (ushort*)(ws + 8388608);       // 6 MB
  ushort* woutT = (ushort*)(ws + 14680064);      // 2 MB
  ushort* qB    = (ushort*)(ws + 16777216);      // 8 MB
  ushort* kB    = (ushort*)(ws + 25165824);      // 8 MB
  ushort* vT    = (ushort*)(ws + 33554432);      // 8 MB (transposed V)
  float2* cs    = (float2*)(ws + 41943040);      // 512 KB (cos,sin packed)
  int*    Lb    = (int*)(ws + 42467328);         // 8 B

  prep<<<8450, 256, 0, stream>>>(hidden, w_qkv, w_out, amask, hO, wqkvT, woutT, cs, Lb);
  gemm_qkv<<<dim3(32, 24), 256, 0, stream>>>(hO, wqkvT, b_qkv, qB, kB, vT, cs);
  attn<<<dim3(32, 32), 256, 0, stream>>>(qB, kB, vT, Lb, hO /* reused as O */);
  gemm_out_k<<<dim3(32, 8), 256, 0, stream>>>(hO, woutT, out);
}